// Round 1
// baseline (14696.394 us; speedup 1.0000x reference)
//
#include <hip/hip_runtime.h>
#include <cstddef>

constexpr int kL = 18, kB = 8, kC = 50, kA = 32, kH = 1024;
constexpr int kNH = 8, kHD = 256, kP = 800, kMLP = 4096;
constexpr int kBC = kB * kC;     // 400 tokens
constexpr int kPT = kP + kC;     // 850 total attention length
constexpr int kQD = kNH * kHD;   // 2048

__device__ __forceinline__ float gelu_tanh(float x) {
  float x3 = x * x * x;
  return 0.5f * x * (1.0f + tanhf(0.7978845608028654f * (x + 0.044715f * x3)));
}

// ---------------------------------------------------------------------------
// Stage 0a: xt[400, 2048] = [noisy @ in_w^T + in_b  |  time_embedding(t)]
// ---------------------------------------------------------------------------
__global__ __launch_bounds__(256) void embed_xt_kernel(
    const float* __restrict__ noisy, const float* __restrict__ ts,
    const float* __restrict__ in_w, const float* __restrict__ in_b,
    float* __restrict__ xt) {
  int idx = blockIdx.x * 256 + threadIdx.x;
  if (idx >= kBC * 2 * kH) return;
  int row = idx / (2 * kH);
  int col = idx - row * (2 * kH);
  float val;
  if (col < kH) {
    const float* nr = noisy + row * kA;
    const float* wr = in_w + (size_t)col * kA;
    float s = in_b[col];
#pragma unroll
    for (int a = 0; a < kA; ++a) s = fmaf(nr[a], wr[a], s);
    val = s;
  } else {
    int j = col - kH;
    int i = (j < kH / 2) ? j : j - kH / 2;
    float frac = (float)i / (float)(kH / 2);
    // period = 4e-3 * 1000^frac
    float period = 4e-3f * expf(frac * 6.907755278982137f);
    float ang = 6.283185307179586f * ts[row / kC] / period;
    val = (j < kH / 2) ? sinf(ang) : cosf(ang);
  }
  xt[idx] = val;
}

// ---------------------------------------------------------------------------
// Generic fp32 GEMM: out[M,N] (+epi) = A[M,K] @ W[N,K]^T
// EPI 0: out = r (+bias); EPI 1: out = silu(r + bias); EPI 2: out += r
// 64x64 tile, BK=16, 256 threads, 4x4 microtile. Requires K % 16 == 0.
// ---------------------------------------------------------------------------
template <int EPI>
__global__ __launch_bounds__(256) void gemm_nt_kernel(
    const float* __restrict__ A, const float* __restrict__ W,
    const float* __restrict__ bias, float* __restrict__ out,
    int M, int N, int K) {
  __shared__ __align__(16) float As[16][68];
  __shared__ __align__(16) float Ws[16][68];
  int tid = threadIdx.x;
  int tx = tid & 15, ty = tid >> 4;
  int m0 = blockIdx.x * 64, n0 = blockIdx.y * 64;
  int lr = tid >> 2, lc = (tid & 3) * 4;
  float acc[4][4] = {};
  for (int k0 = 0; k0 < K; k0 += 16) {
    float4 a4 = make_float4(0.f, 0.f, 0.f, 0.f);
    int m = m0 + lr;
    if (m < M) a4 = *(const float4*)(A + (size_t)m * K + k0 + lc);
    As[lc + 0][lr] = a4.x; As[lc + 1][lr] = a4.y;
    As[lc + 2][lr] = a4.z; As[lc + 3][lr] = a4.w;
    float4 w4 = make_float4(0.f, 0.f, 0.f, 0.f);
    int n = n0 + lr;
    if (n < N) w4 = *(const float4*)(W + (size_t)n * K + k0 + lc);
    Ws[lc + 0][lr] = w4.x; Ws[lc + 1][lr] = w4.y;
    Ws[lc + 2][lr] = w4.z; Ws[lc + 3][lr] = w4.w;
    __syncthreads();
#pragma unroll
    for (int kk = 0; kk < 16; ++kk) {
      float a[4], w[4];
#pragma unroll
      for (int i = 0; i < 4; ++i) a[i] = As[kk][ty * 4 + i];
#pragma unroll
      for (int j = 0; j < 4; ++j) w[j] = Ws[kk][tx * 4 + j];
#pragma unroll
      for (int i = 0; i < 4; ++i)
#pragma unroll
        for (int j = 0; j < 4; ++j) acc[i][j] = fmaf(a[i], w[j], acc[i][j]);
    }
    __syncthreads();
  }
#pragma unroll
  for (int i = 0; i < 4; ++i) {
    int m = m0 + ty * 4 + i;
    if (m >= M) continue;
#pragma unroll
    for (int j = 0; j < 4; ++j) {
      int n = n0 + tx * 4 + j;
      if (n >= N) continue;
      float r = acc[i][j];
      size_t oi = (size_t)m * N + n;
      if (EPI == 0) {
        if (bias) r += bias[n];
        out[oi] = r;
      } else if (EPI == 1) {
        r += bias[n];
        out[oi] = r / (1.0f + expf(-r));
      } else {  // EPI == 2
        out[oi] += r;
      }
    }
  }
}

// ---------------------------------------------------------------------------
// Fused QKV projection: h[400,1024] x {q_w[2048,1024], k_w[256,1024],
// v_w[256,1024]} -> q[400,2048], k[400,256], v[400,256]. grid (7, 40).
// ---------------------------------------------------------------------------
__global__ __launch_bounds__(256) void gemm_qkv_kernel(
    const float* __restrict__ A, const float* __restrict__ Wq,
    const float* __restrict__ Wk, const float* __restrict__ Wv,
    float* __restrict__ q, float* __restrict__ k, float* __restrict__ v) {
  __shared__ __align__(16) float As[16][68];
  __shared__ __align__(16) float Ws[16][68];
  int tid = threadIdx.x;
  int tx = tid & 15, ty = tid >> 4;
  int m0 = blockIdx.x * 64, n0 = blockIdx.y * 64;
  const float* W;
  float* out;
  int nbase, ostride;
  if (n0 < kQD) { W = Wq; out = q; nbase = n0; ostride = kQD; }
  else if (n0 < kQD + kHD) { W = Wk; out = k; nbase = n0 - kQD; ostride = kHD; }
  else { W = Wv; out = v; nbase = n0 - kQD - kHD; ostride = kHD; }
  int lr = tid >> 2, lc = (tid & 3) * 4;
  float acc[4][4] = {};
  for (int k0 = 0; k0 < kH; k0 += 16) {
    float4 a4 = make_float4(0.f, 0.f, 0.f, 0.f);
    int m = m0 + lr;
    if (m < kBC) a4 = *(const float4*)(A + (size_t)m * kH + k0 + lc);
    As[lc + 0][lr] = a4.x; As[lc + 1][lr] = a4.y;
    As[lc + 2][lr] = a4.z; As[lc + 3][lr] = a4.w;
    float4 w4 = *(const float4*)(W + (size_t)(nbase + lr) * kH + k0 + lc);
    Ws[lc + 0][lr] = w4.x; Ws[lc + 1][lr] = w4.y;
    Ws[lc + 2][lr] = w4.z; Ws[lc + 3][lr] = w4.w;
    __syncthreads();
#pragma unroll
    for (int kk = 0; kk < 16; ++kk) {
      float a[4], w[4];
#pragma unroll
      for (int i = 0; i < 4; ++i) a[i] = As[kk][ty * 4 + i];
#pragma unroll
      for (int j = 0; j < 4; ++j) w[j] = Ws[kk][tx * 4 + j];
#pragma unroll
      for (int i = 0; i < 4; ++i)
#pragma unroll
        for (int j = 0; j < 4; ++j) acc[i][j] = fmaf(a[i], w[j], acc[i][j]);
    }
    __syncthreads();
  }
#pragma unroll
  for (int i = 0; i < 4; ++i) {
    int m = m0 + ty * 4 + i;
    if (m >= kBC) continue;
#pragma unroll
    for (int j = 0; j < 4; ++j) {
      out[(size_t)m * ostride + nbase + tx * 4 + j] = acc[i][j];
    }
  }
}

// ---------------------------------------------------------------------------
// RMSNorm: one block per row. h = x * rsqrt(mean(x^2)+eps) * w
// ---------------------------------------------------------------------------
__global__ __launch_bounds__(256) void rmsnorm_kernel(
    const float* __restrict__ x, const float* __restrict__ w,
    float* __restrict__ h) {
  int row = blockIdx.x;
  const float* xr = x + (size_t)row * kH;
  float s = 0.f;
  for (int i = threadIdx.x; i < kH; i += 256) { float v = xr[i]; s = fmaf(v, v, s); }
  __shared__ float red[256];
  red[threadIdx.x] = s;
  __syncthreads();
  for (int st = 128; st > 0; st >>= 1) {
    if (threadIdx.x < st) red[threadIdx.x] += red[threadIdx.x + st];
    __syncthreads();
  }
  float rs = rsqrtf(red[0] / (float)kH + 1e-6f);
  for (int i = threadIdx.x; i < kH; i += 256) h[(size_t)row * kH + i] = xr[i] * rs * w[i];
}

// ---------------------------------------------------------------------------
// RoPE for q and k; also reorders q -> q_r[B,NH,C,HD], k -> k_r[B,C,HD]
// ---------------------------------------------------------------------------
__global__ __launch_bounds__(256) void rope_kernel(
    const float* __restrict__ q, const float* __restrict__ k,
    const int* __restrict__ pos_ids, float* __restrict__ q_r,
    float* __restrict__ k_r) {
  int idx = blockIdx.x * 256 + threadIdx.x;
  const int NQ = kBC * kNH * (kHD / 2);  // 409600
  const int NK = kBC * (kHD / 2);        // 51200
  if (idx >= NQ + NK) return;
  if (idx < NQ) {
    int i = idx & 127;
    int rem = idx >> 7;
    int n = rem & 7;
    int row = rem >> 3;
    int b = row / kC, c = row - b * kC;
    float p = (float)pos_ids[c];
    float inv = expf(-((float)i / 128.0f) * 9.210340371976184f);  // ln(10000)
    float ang = p * inv;
    float cs = cosf(ang), sn = sinf(ang);
    const float* src = q + (size_t)row * kQD + n * kHD;
    float x1 = src[i], x2 = src[i + 128];
    float* dst = q_r + (((size_t)(b * kNH + n)) * kC + c) * kHD;
    dst[i] = x1 * cs - x2 * sn;
    dst[i + 128] = x2 * cs + x1 * sn;
  } else {
    int t = idx - NQ;
    int i = t & 127;
    int row = t >> 7;
    int b = row / kC, c = row - b * kC;
    float p = (float)pos_ids[c];
    float inv = expf(-((float)i / 128.0f) * 9.210340371976184f);
    float ang = p * inv;
    float cs = cosf(ang), sn = sinf(ang);
    const float* src = k + (size_t)row * kHD;
    float x1 = src[i], x2 = src[i + 128];
    float* dst = k_r + ((size_t)b * kC + c) * kHD;
    dst[i] = x1 * cs - x2 * sn;
    dst[i + 128] = x2 * cs + x1 * sn;
  }
}

// ---------------------------------------------------------------------------
// Attention scores: S[b, (n,c), t] = (q_r[b] @ kk[b]^T) / 16
// kk row t: prefix_k (t<800) else local rope'd k. grid (7, 14, 8).
// ---------------------------------------------------------------------------
__global__ __launch_bounds__(256) void attn_scores_kernel(
    const float* __restrict__ q_r, const float* __restrict__ pk,
    const float* __restrict__ k_r, float* __restrict__ S) {
  int b = blockIdx.z;
  int m0 = blockIdx.x * 64, t0 = blockIdx.y * 64;
  const float* Aq = q_r + (size_t)b * kNH * kC * kHD;
  __shared__ __align__(16) float As[16][68];
  __shared__ __align__(16) float Ws[16][68];
  int tid = threadIdx.x;
  int tx = tid & 15, ty = tid >> 4;
  int lr = tid >> 2, lc = (tid & 3) * 4;
  float acc[4][4] = {};
  for (int k0 = 0; k0 < kHD; k0 += 16) {
    float4 a4 = make_float4(0.f, 0.f, 0.f, 0.f);
    int m = m0 + lr;
    if (m < kNH * kC) a4 = *(const float4*)(Aq + (size_t)m * kHD + k0 + lc);
    As[lc + 0][lr] = a4.x; As[lc + 1][lr] = a4.y;
    As[lc + 2][lr] = a4.z; As[lc + 3][lr] = a4.w;
    float4 w4 = make_float4(0.f, 0.f, 0.f, 0.f);
    int t = t0 + lr;
    if (t < kP) w4 = *(const float4*)(pk + ((size_t)b * kP + t) * kHD + k0 + lc);
    else if (t < kPT) w4 = *(const float4*)(k_r + ((size_t)b * kC + (t - kP)) * kHD + k0 + lc);
    Ws[lc + 0][lr] = w4.x; Ws[lc + 1][lr] = w4.y;
    Ws[lc + 2][lr] = w4.z; Ws[lc + 3][lr] = w4.w;
    __syncthreads();
#pragma unroll
    for (int kk = 0; kk < 16; ++kk) {
      float a[4], w[4];
#pragma unroll
      for (int i = 0; i < 4; ++i) a[i] = As[kk][ty * 4 + i];
#pragma unroll
      for (int j = 0; j < 4; ++j) w[j] = Ws[kk][tx * 4 + j];
#pragma unroll
      for (int i = 0; i < 4; ++i)
#pragma unroll
        for (int j = 0; j < 4; ++j) acc[i][j] = fmaf(a[i], w[j], acc[i][j]);
    }
    __syncthreads();
  }
#pragma unroll
  for (int i = 0; i < 4; ++i) {
    int m = m0 + ty * 4 + i;
    if (m >= kNH * kC) continue;
#pragma unroll
    for (int j = 0; j < 4; ++j) {
      int t = t0 + tx * 4 + j;
      if (t < kPT) S[((size_t)b * (kNH * kC) + m) * kPT + t] = acc[i][j] * 0.0625f;
    }
  }
}

// ---------------------------------------------------------------------------
// Row softmax over 850 entries, in place. grid = 3200 rows.
// ---------------------------------------------------------------------------
__global__ __launch_bounds__(256) void softmax_kernel(float* __restrict__ S) {
  size_t row = blockIdx.x;
  float* r = S + row * kPT;
  __shared__ float buf[kPT];
  __shared__ float red[256];
  float mx = -1e30f;
  for (int i = threadIdx.x; i < kPT; i += 256) {
    buf[i] = r[i];
    mx = fmaxf(mx, buf[i]);
  }
  red[threadIdx.x] = mx;
  __syncthreads();
  for (int st = 128; st > 0; st >>= 1) {
    if (threadIdx.x < st) red[threadIdx.x] = fmaxf(red[threadIdx.x], red[threadIdx.x + st]);
    __syncthreads();
  }
  mx = red[0];
  __syncthreads();
  float s = 0.f;
  for (int i = threadIdx.x; i < kPT; i += 256) {
    float e = expf(buf[i] - mx);
    buf[i] = e;
    s += e;
  }
  red[threadIdx.x] = s;
  __syncthreads();
  for (int st = 128; st > 0; st >>= 1) {
    if (threadIdx.x < st) red[threadIdx.x] += red[threadIdx.x + st];
    __syncthreads();
  }
  float inv = 1.0f / red[0];
  for (int i = threadIdx.x; i < kPT; i += 256) r[i] = buf[i] * inv;
}

// ---------------------------------------------------------------------------
// o = attn @ V, written token-major: o_tok[(b,c), n*256+d]. grid (7, 4, 8).
// V row t: prefix_v (t<800) else local v (token-major [400,256]).
// ---------------------------------------------------------------------------
__global__ __launch_bounds__(256) void attn_av_kernel(
    const float* __restrict__ S, const float* __restrict__ pv,
    const float* __restrict__ v, float* __restrict__ o_tok) {
  int b = blockIdx.z;
  int m0 = blockIdx.x * 64, d0 = blockIdx.y * 64;
  const float* Sb = S + (size_t)b * (kNH * kC) * kPT;
  __shared__ __align__(16) float As[16][68];
  __shared__ __align__(16) float Ws[16][68];
  int tid = threadIdx.x;
  int tx = tid & 15, ty = tid >> 4;
  int alr = tid >> 2, alc = (tid & 3) * 4;   // A: 64 rows x 16 t, scalar loads
  int wtr = tid >> 4, wdc = (tid & 15) * 4;  // W: 16 t-rows x 64 d, float4
  float acc[4][4] = {};
  for (int t0 = 0; t0 < kPT; t0 += 16) {
    int m = m0 + alr;
#pragma unroll
    for (int ii = 0; ii < 4; ++ii) {
      int t = t0 + alc + ii;
      As[alc + ii][alr] =
          (m < kNH * kC && t < kPT) ? Sb[(size_t)m * kPT + t] : 0.f;
    }
    {
      int t = t0 + wtr;
      float4 w4 = make_float4(0.f, 0.f, 0.f, 0.f);
      if (t < kP) w4 = *(const float4*)(pv + ((size_t)b * kP + t) * kHD + d0 + wdc);
      else if (t < kPT) w4 = *(const float4*)(v + ((size_t)(b * kC + (t - kP))) * kHD + d0 + wdc);
      *(float4*)&Ws[wtr][wdc] = w4;
    }
    __syncthreads();
#pragma unroll
    for (int kk = 0; kk < 16; ++kk) {
      float a[4], w[4];
#pragma unroll
      for (int i = 0; i < 4; ++i) a[i] = As[kk][ty * 4 + i];
#pragma unroll
      for (int j = 0; j < 4; ++j) w[j] = Ws[kk][tx * 4 + j];
#pragma unroll
      for (int i = 0; i < 4; ++i)
#pragma unroll
        for (int j = 0; j < 4; ++j) acc[i][j] = fmaf(a[i], w[j], acc[i][j]);
    }
    __syncthreads();
  }
#pragma unroll
  for (int i = 0; i < 4; ++i) {
    int m = m0 + ty * 4 + i;  // m = n*C + c
    if (m >= kNH * kC) continue;
    int n = m / kC, c = m - n * kC;
#pragma unroll
    for (int j = 0; j < 4; ++j) {
      int d = d0 + tx * 4 + j;
      o_tok[((size_t)(b * kC + c)) * kQD + n * kHD + d] = acc[i][j];
    }
  }
}

// ---------------------------------------------------------------------------
// Fused MLP gate+up: mid[400,4096] = gelu(h @ Wg^T) * (h @ Wu^T). grid (7,64).
// ---------------------------------------------------------------------------
__global__ __launch_bounds__(256) void mlp_gateup_kernel(
    const float* __restrict__ A, const float* __restrict__ Wg,
    const float* __restrict__ Wu, float* __restrict__ mid) {
  __shared__ __align__(16) float As[16][68];
  __shared__ __align__(16) float Gs[16][68];
  __shared__ __align__(16) float Us[16][68];
  int tid = threadIdx.x;
  int tx = tid & 15, ty = tid >> 4;
  int m0 = blockIdx.x * 64, n0 = blockIdx.y * 64;
  int lr = tid >> 2, lc = (tid & 3) * 4;
  float accg[4][4] = {}, accu[4][4] = {};
  for (int k0 = 0; k0 < kH; k0 += 16) {
    float4 a4 = make_float4(0.f, 0.f, 0.f, 0.f);
    int m = m0 + lr;
    if (m < kBC) a4 = *(const float4*)(A + (size_t)m * kH + k0 + lc);
    As[lc + 0][lr] = a4.x; As[lc + 1][lr] = a4.y;
    As[lc + 2][lr] = a4.z; As[lc + 3][lr] = a4.w;
    float4 g4 = *(const float4*)(Wg + (size_t)(n0 + lr) * kH + k0 + lc);
    Gs[lc + 0][lr] = g4.x; Gs[lc + 1][lr] = g4.y;
    Gs[lc + 2][lr] = g4.z; Gs[lc + 3][lr] = g4.w;
    float4 u4 = *(const float4*)(Wu + (size_t)(n0 + lr) * kH + k0 + lc);
    Us[lc + 0][lr] = u4.x; Us[lc + 1][lr] = u4.y;
    Us[lc + 2][lr] = u4.z; Us[lc + 3][lr] = u4.w;
    __syncthreads();
#pragma unroll
    for (int kk = 0; kk < 16; ++kk) {
      float a[4], g[4], u[4];
#pragma unroll
      for (int i = 0; i < 4; ++i) a[i] = As[kk][ty * 4 + i];
#pragma unroll
      for (int j = 0; j < 4; ++j) g[j] = Gs[kk][tx * 4 + j];
#pragma unroll
      for (int j = 0; j < 4; ++j) u[j] = Us[kk][tx * 4 + j];
#pragma unroll
      for (int i = 0; i < 4; ++i) {
#pragma unroll
        for (int j = 0; j < 4; ++j) {
          accg[i][j] = fmaf(a[i], g[j], accg[i][j]);
          accu[i][j] = fmaf(a[i], u[j], accu[i][j]);
        }
      }
    }
    __syncthreads();
  }
#pragma unroll
  for (int i = 0; i < 4; ++i) {
    int m = m0 + ty * 4 + i;
    if (m >= kBC) continue;
#pragma unroll
    for (int j = 0; j < 4; ++j) {
      int n = n0 + tx * 4 + j;
      mid[(size_t)m * kMLP + n] = gelu_tanh(accg[i][j]) * accu[i][j];
    }
  }
}

// ---------------------------------------------------------------------------
extern "C" void kernel_launch(void* const* d_in, const int* in_sizes, int n_in,
                              void* d_out, int out_size, void* d_ws,
                              size_t ws_size, hipStream_t stream) {
  const float* noisy       = (const float*)d_in[0];
  const float* timestep    = (const float*)d_in[1];
  const int*   pos_ids     = (const int*)d_in[2];
  const float* prefix_k    = (const float*)d_in[3];
  const float* prefix_v    = (const float*)d_in[4];
  const float* in_w        = (const float*)d_in[5];
  const float* in_b        = (const float*)d_in[6];
  const float* t_in_w      = (const float*)d_in[7];
  const float* t_in_b      = (const float*)d_in[8];
  const float* t_out_w     = (const float*)d_in[9];
  const float* t_out_b     = (const float*)d_in[10];
  const float* out_w       = (const float*)d_in[11];
  const float* out_b       = (const float*)d_in[12];
  const float* final_norm_w= (const float*)d_in[13];
  const float* ln1_w       = (const float*)d_in[14];
  const float* q_w         = (const float*)d_in[15];
  const float* k_w         = (const float*)d_in[16];
  const float* v_w         = (const float*)d_in[17];
  const float* o_w         = (const float*)d_in[18];
  const float* ln2_w       = (const float*)d_in[19];
  const float* gate_w      = (const float*)d_in[20];
  const float* up_w        = (const float*)d_in[21];
  const float* down_w      = (const float*)d_in[22];

  float* ws = (float*)d_ws;
  float* x     = ws;  ws += (size_t)kBC * kH;        // 409600
  float* h     = ws;  ws += (size_t)kBC * kH;        // 409600
  float* xt    = ws;  ws += (size_t)kBC * 2 * kH;    // 819200
  float* u     = ws;  ws += (size_t)kBC * kH;        // 409600
  float* q     = ws;  ws += (size_t)kBC * kQD;       // 819200
  float* k     = ws;  ws += (size_t)kBC * kHD;       // 102400
  float* v     = ws;  ws += (size_t)kBC * kHD;       // 102400
  float* q_r   = ws;  ws += (size_t)kB * kNH * kC * kHD;  // 819200
  float* k_r   = ws;  ws += (size_t)kB * kC * kHD;   // 102400
  float* S     = ws;  ws += (size_t)kB * kNH * kC * kPT;  // 2720000
  float* o_tok = ws;  ws += (size_t)kBC * kQD;       // 819200
  float* mid   = ws;  ws += (size_t)kBC * kMLP;      // 1638400

  // ---- stage 0: action embed + time embed + fused action-time MLP ----
  embed_xt_kernel<<<(kBC * 2 * kH + 255) / 256, 256, 0, stream>>>(
      noisy, timestep, in_w, in_b, xt);
  gemm_nt_kernel<1><<<dim3(7, 16), 256, 0, stream>>>(xt, t_in_w, t_in_b, u,
                                                     kBC, kH, 2 * kH);
  gemm_nt_kernel<0><<<dim3(7, 16), 256, 0, stream>>>(u, t_out_w, t_out_b, x,
                                                     kBC, kH, kH);

  // ---- 18 transformer layers ----
  for (int l = 0; l < kL; ++l) {
    const float* pk_l = prefix_k + (size_t)l * kB * kP * kHD;
    const float* pv_l = prefix_v + (size_t)l * kB * kP * kHD;

    rmsnorm_kernel<<<kBC, 256, 0, stream>>>(x, ln1_w + (size_t)l * kH, h);
    gemm_qkv_kernel<<<dim3(7, 40), 256, 0, stream>>>(
        h, q_w + (size_t)l * kQD * kH, k_w + (size_t)l * kHD * kH,
        v_w + (size_t)l * kHD * kH, q, k, v);
    rope_kernel<<<(kBC * kNH * 128 + kBC * 128 + 255) / 256, 256, 0, stream>>>(
        q, k, pos_ids, q_r, k_r);
    attn_scores_kernel<<<dim3(7, 14, 8), 256, 0, stream>>>(q_r, pk_l, k_r, S);
    softmax_kernel<<<kB * kNH * kC, 256, 0, stream>>>(S);
    attn_av_kernel<<<dim3(7, 4, 8), 256, 0, stream>>>(S, pv_l, v, o_tok);
    gemm_nt_kernel<2><<<dim3(7, 16), 256, 0, stream>>>(
        o_tok, o_w + (size_t)l * kH * kQD, nullptr, x, kBC, kH, kQD);
    rmsnorm_kernel<<<kBC, 256, 0, stream>>>(x, ln2_w + (size_t)l * kH, h);
    mlp_gateup_kernel<<<dim3(7, 64), 256, 0, stream>>>(
        h, gate_w + (size_t)l * kMLP * kH, up_w + (size_t)l * kMLP * kH, mid);
    gemm_nt_kernel<2><<<dim3(7, 16), 256, 0, stream>>>(
        mid, down_w + (size_t)l * kH * kMLP, nullptr, x, kBC, kH, kMLP);
  }

  // ---- final norm + output projection ----
  rmsnorm_kernel<<<kBC, 256, 0, stream>>>(x, final_norm_w, h);
  gemm_nt_kernel<0><<<dim3(7, 1), 256, 0, stream>>>(h, out_w, out_b,
                                                    (float*)d_out, kBC, kA, kH);
}